// Round 1
// baseline (3884.997 us; speedup 1.0000x reference)
//
#include <hip/hip_runtime.h>

#define E_N       32768
#define S_N       16
#define H_N       128
#define N_DST_N   5000
#define NCLS      10

// ---------------------------------------------------------------------------
// Edge mega-kernel: one block (256 threads) per edge.
// embed -> 2 x (attn + LN + FF + LN) -> masked mean pool -> W_eout matmul
// -> relu -> atomicAdd into h_agg[dst].
// LDS: e_lds [16][136], qkv_lds [16][392] (q region reused for ctx / ffh).
// ---------------------------------------------------------------------------

__device__ __forceinline__ void matvec8(const float* __restrict__ W,   // [128 x 128] k-major
                                        const float* src, int pitch,   // LDS base, row pitch
                                        int r0, int c, float acc[8]) {
#pragma unroll 4
    for (int k = 0; k < 128; ++k) {
        float w = W[k * 128 + c];
#pragma unroll
        for (int r = 0; r < 8; ++r)
            acc[r] = fmaf(src[(r0 + r) * pitch + k], w, acc[r]);
    }
}

__global__ __launch_bounds__(256, 4) void edge_kernel(
    const float* __restrict__ node_features,   // [N_SRC,128]
    const float* __restrict__ edge_features,   // [E,16,15]
    const float* __restrict__ seq_times,       // [E,16]
    const int*   __restrict__ e_len,           // [E]
    const int*   __restrict__ src_ids,         // [E]
    const int*   __restrict__ dst_ids,         // [E]
    const float* __restrict__ W_ein,           // [16,128]
    const float* __restrict__ b_ein,           // [128]
    const float* __restrict__ Wqkv,            // [2,128,384]
    const float* __restrict__ bqkv,            // [2,384]
    const float* __restrict__ Wo,              // [2,128,128]
    const float* __restrict__ bo,              // [2,128]
    const float* __restrict__ ln1_g, const float* __restrict__ ln1_b,  // [2,128]
    const float* __restrict__ W1, const float* __restrict__ b1,        // [2,128,128],[2,128]
    const float* __restrict__ W2, const float* __restrict__ b2,
    const float* __restrict__ ln2_g, const float* __restrict__ ln2_b,
    const float* __restrict__ W_eout,          // [256,128]
    const float* __restrict__ b_eout,          // [128]
    float* __restrict__ h_agg)                 // [N_DST,128]
{
    __shared__ float e_lds[16][136];
    __shared__ float qkv_lds[16][392];
    __shared__ float x_lds[16][16];
    __shared__ float pool_lds[128];
    __shared__ float hsrc_lds[128];

    const int tid  = threadIdx.x;
    const int eidx = blockIdx.x;
    const int c    = tid & 127;
    const int half = tid >> 7;
    const int r0   = half * 8;

    const int len = e_len[eidx];
    const int src = src_ids[eidx];
    const int dst = dst_ids[eidx];

    // ---- stage input row [16 feats] per token ----
    {
        int s = tid >> 4, i = tid & 15;
        float v = (i < 15) ? edge_features[eidx * 240 + s * 15 + i]
                           : seq_times[eidx * 16 + s];
        x_lds[s][i] = v;
    }
    __syncthreads();

    // ---- embed: e = relu(x @ W_ein + b_ein) ----
    {
        float acc[8];
#pragma unroll
        for (int r = 0; r < 8; ++r) acc[r] = 0.f;
#pragma unroll
        for (int i = 0; i < 16; ++i) {
            float w = W_ein[i * 128 + c];
#pragma unroll
            for (int r = 0; r < 8; ++r)
                acc[r] = fmaf(x_lds[r0 + r][i], w, acc[r]);
        }
        float bv = b_ein[c];
#pragma unroll
        for (int r = 0; r < 8; ++r)
            e_lds[r0 + r][c] = fmaxf(acc[r] + bv, 0.f);
    }
    __syncthreads();

    // ---- 2 transformer layers ----
    for (int l = 0; l < 2; ++l) {
        // qkv = e @ Wqkv + bqkv     (thread owns cols c, c+128, c+256; rows r0..r0+7)
        {
            const float* Wq = Wqkv + l * (128 * 384);
            const float* bq = bqkv + l * 384;
            float a0[8], a1[8], a2[8];
#pragma unroll
            for (int r = 0; r < 8; ++r) { a0[r] = 0.f; a1[r] = 0.f; a2[r] = 0.f; }
#pragma unroll 4
            for (int k = 0; k < 128; ++k) {
                float w0 = Wq[k * 384 + c];
                float w1 = Wq[k * 384 + c + 128];
                float w2 = Wq[k * 384 + c + 256];
#pragma unroll
                for (int r = 0; r < 8; ++r) {
                    float ev = e_lds[r0 + r][k];
                    a0[r] = fmaf(ev, w0, a0[r]);
                    a1[r] = fmaf(ev, w1, a1[r]);
                    a2[r] = fmaf(ev, w2, a2[r]);
                }
            }
            float b0v = bq[c], b1v = bq[c + 128], b2v = bq[c + 256];
#pragma unroll
            for (int r = 0; r < 8; ++r) {
                qkv_lds[r0 + r][c]       = a0[r] + b0v;
                qkv_lds[r0 + r][c + 128] = a1[r] + b1v;
                qkv_lds[r0 + r][c + 256] = a2[r] + b2v;
            }
        }
        __syncthreads();

        // attention: thread (h,q) for tid<128; ctx written into own q-slot
        if (tid < 128) {
            int hh = tid >> 4, qq = tid & 15;
            int hb = hh * 16;
            float qv[16];
#pragma unroll
            for (int d = 0; d < 16; ++d) qv[d] = qkv_lds[qq][hb + d];
            float sc[16];
            float mx = -1e30f;
#pragma unroll
            for (int kk = 0; kk < 16; ++kk) {
                float s = 0.f;
#pragma unroll
                for (int d = 0; d < 16; ++d)
                    s = fmaf(qv[d], qkv_lds[kk][128 + hb + d], s);
                s *= 0.25f;             // 1/sqrt(16)
                sc[kk] = s;
                mx = fmaxf(mx, (kk < len) ? s : -1e30f);
            }
            float sum = 0.f;
#pragma unroll
            for (int kk = 0; kk < 16; ++kk) {
                float p = (kk < len) ? __expf(sc[kk] - mx) : 0.f;
                sc[kk] = p;
                sum += p;
            }
            float invs = 1.f / sum;
            float ctx[16];
#pragma unroll
            for (int d = 0; d < 16; ++d) ctx[d] = 0.f;
#pragma unroll
            for (int kk = 0; kk < 16; ++kk) {
                float p = sc[kk] * invs;
#pragma unroll
                for (int d = 0; d < 16; ++d)
                    ctx[d] = fmaf(p, qkv_lds[kk][256 + hb + d], ctx[d]);
            }
#pragma unroll
            for (int d = 0; d < 16; ++d) qkv_lds[qq][hb + d] = ctx[d];
        }
        __syncthreads();

        // proj + residual: e += ctx @ Wo + bo
        {
            float acc[8];
#pragma unroll
            for (int r = 0; r < 8; ++r) acc[r] = 0.f;
            matvec8(Wo + l * (128 * 128), &qkv_lds[0][0], 392, r0, c, acc);
            float bv = bo[l * 128 + c];
#pragma unroll
            for (int r = 0; r < 8; ++r)
                e_lds[r0 + r][c] += acc[r] + bv;
        }
        __syncthreads();

        // LN1 (in place): 16 lanes per row
        {
            const float* g = ln1_g + l * 128;
            const float* b = ln1_b + l * 128;
            int r = tid >> 4, j = tid & 15;
            float vals[8];
#pragma unroll
            for (int m = 0; m < 8; ++m) vals[m] = e_lds[r][j + 16 * m];
            float s = 0.f;
#pragma unroll
            for (int m = 0; m < 8; ++m) s += vals[m];
            s += __shfl_xor(s, 1); s += __shfl_xor(s, 2);
            s += __shfl_xor(s, 4); s += __shfl_xor(s, 8);
            float mu = s * (1.f / 128.f);
            float v = 0.f;
#pragma unroll
            for (int m = 0; m < 8; ++m) { float d = vals[m] - mu; v = fmaf(d, d, v); }
            v += __shfl_xor(v, 1); v += __shfl_xor(v, 2);
            v += __shfl_xor(v, 4); v += __shfl_xor(v, 8);
            float inv = rsqrtf(v * (1.f / 128.f) + 1e-5f);
#pragma unroll
            for (int m = 0; m < 8; ++m) {
                int col = j + 16 * m;
                e_lds[r][col] = (vals[m] - mu) * inv * g[col] + b[col];
            }
        }
        __syncthreads();

        // FF1: ffh = relu(e @ W1 + b1)  -> qkv_lds cols 0..127
        {
            float acc[8];
#pragma unroll
            for (int r = 0; r < 8; ++r) acc[r] = 0.f;
            matvec8(W1 + l * (128 * 128), &e_lds[0][0], 136, r0, c, acc);
            float bv = b1[l * 128 + c];
#pragma unroll
            for (int r = 0; r < 8; ++r)
                qkv_lds[r0 + r][c] = fmaxf(acc[r] + bv, 0.f);
        }
        __syncthreads();

        // FF2 + residual: e += ffh @ W2 + b2
        {
            float acc[8];
#pragma unroll
            for (int r = 0; r < 8; ++r) acc[r] = 0.f;
            matvec8(W2 + l * (128 * 128), &qkv_lds[0][0], 392, r0, c, acc);
            float bv = b2[l * 128 + c];
#pragma unroll
            for (int r = 0; r < 8; ++r)
                e_lds[r0 + r][c] += acc[r] + bv;
        }
        __syncthreads();

        // LN2 (in place)
        {
            const float* g = ln2_g + l * 128;
            const float* b = ln2_b + l * 128;
            int r = tid >> 4, j = tid & 15;
            float vals[8];
#pragma unroll
            for (int m = 0; m < 8; ++m) vals[m] = e_lds[r][j + 16 * m];
            float s = 0.f;
#pragma unroll
            for (int m = 0; m < 8; ++m) s += vals[m];
            s += __shfl_xor(s, 1); s += __shfl_xor(s, 2);
            s += __shfl_xor(s, 4); s += __shfl_xor(s, 8);
            float mu = s * (1.f / 128.f);
            float v = 0.f;
#pragma unroll
            for (int m = 0; m < 8; ++m) { float d = vals[m] - mu; v = fmaf(d, d, v); }
            v += __shfl_xor(v, 1); v += __shfl_xor(v, 2);
            v += __shfl_xor(v, 4); v += __shfl_xor(v, 8);
            float inv = rsqrtf(v * (1.f / 128.f) + 1e-5f);
#pragma unroll
            for (int m = 0; m < 8; ++m) {
                int col = j + 16 * m;
                e_lds[r][col] = (vals[m] - mu) * inv * g[col] + b[col];
            }
        }
        __syncthreads();
    }

    // ---- masked mean pool + gather h[src] ----
    if (tid < 128) {
        float s = 0.f;
#pragma unroll
        for (int ss = 0; ss < 16; ++ss)
            s += (ss < len) ? e_lds[ss][tid] : 0.f;
        pool_lds[tid] = s / (float)len;
        hsrc_lds[tid] = node_features[src * 128 + tid];
    }
    __syncthreads();

    // ---- m = relu(concat(h_src, pooled) @ W_eout + b_eout); atomic segment sum ----
    if (tid < 128) {
        float acc = 0.f;
#pragma unroll 4
        for (int k = 0; k < 128; ++k)
            acc = fmaf(hsrc_lds[k], W_eout[k * 128 + tid], acc);
#pragma unroll 4
        for (int k = 0; k < 128; ++k)
            acc = fmaf(pool_lds[k], W_eout[(128 + k) * 128 + tid], acc);
        acc += b_eout[tid];
        atomicAdd(&h_agg[dst * 128 + tid], fmaxf(acc, 0.f));
    }
}

// ---------------------------------------------------------------------------
// Node update kernel: one block (128 threads) per destination node.
// ---------------------------------------------------------------------------
__global__ __launch_bounds__(128) void node_kernel(
    const float* __restrict__ node_features,
    const int*   __restrict__ layer_nid,
    const float* __restrict__ subg_norm,
    const float* __restrict__ h_agg,
    const float* __restrict__ W_eout, const float* __restrict__ b_eout,
    const float* __restrict__ W_node, const float* __restrict__ b_node,
    const float* __restrict__ W_fc,   const float* __restrict__ b_fc,
    float* __restrict__ out)
{
    __shared__ float sh[128];
    __shared__ float hh[128];
    __shared__ float z[128];

    const int n   = blockIdx.x;
    const int tid = threadIdx.x;
    const int nid = layer_nid[n];
    const float norm = subg_norm[n];

    sh[tid] = node_features[nid * 128 + tid];
    __syncthreads();

    // self_h_tmp = concat(self_h, 0) @ W_eout + b_eout  (only first 128 rows matter)
    float acc = 0.f;
#pragma unroll 4
    for (int k = 0; k < 128; ++k)
        acc = fmaf(sh[k], W_eout[k * 128 + tid], acc);
    acc += b_eout[tid];
    hh[tid] = (h_agg[n * 128 + tid] - acc) * norm;
    __syncthreads();

    // z = relu(concat(self_h, hh) @ W_node + b_node)
    float za = 0.f;
#pragma unroll 4
    for (int k = 0; k < 128; ++k)
        za = fmaf(sh[k], W_node[k * 128 + tid], za);
#pragma unroll 4
    for (int k = 0; k < 128; ++k)
        za = fmaf(hh[k], W_node[(128 + k) * 128 + tid], za);
    za += b_node[tid];
    z[tid] = fmaxf(za, 0.f);
    __syncthreads();

    // out = z @ W_fc + b_fc
    if (tid < NCLS) {
        float o = 0.f;
#pragma unroll 4
        for (int k = 0; k < 128; ++k)
            o = fmaf(z[k], W_fc[k * NCLS + tid], o);
        out[n * NCLS + tid] = o + b_fc[tid];
    }
}

// ---------------------------------------------------------------------------

extern "C" void kernel_launch(void* const* d_in, const int* in_sizes, int n_in,
                              void* d_out, int out_size, void* d_ws, size_t ws_size,
                              hipStream_t stream) {
    const float* node_features = (const float*)d_in[0];
    const float* edge_features = (const float*)d_in[1];
    const float* seq_times     = (const float*)d_in[2];
    const int*   e_len         = (const int*)d_in[3];
    // d_in[4] = e_mask (unused; recomputed from e_len)
    const int*   src_ids       = (const int*)d_in[5];
    const int*   dst_ids       = (const int*)d_in[6];
    const int*   layer_nid     = (const int*)d_in[7];
    const float* subg_norm     = (const float*)d_in[8];
    const float* W_ein  = (const float*)d_in[9];
    const float* b_ein  = (const float*)d_in[10];
    const float* Wqkv   = (const float*)d_in[11];
    const float* bqkv   = (const float*)d_in[12];
    const float* Wo     = (const float*)d_in[13];
    const float* bo     = (const float*)d_in[14];
    const float* ln1_g  = (const float*)d_in[15];
    const float* ln1_b  = (const float*)d_in[16];
    const float* W1     = (const float*)d_in[17];
    const float* b1     = (const float*)d_in[18];
    const float* W2     = (const float*)d_in[19];
    const float* b2     = (const float*)d_in[20];
    const float* ln2_g  = (const float*)d_in[21];
    const float* ln2_b  = (const float*)d_in[22];
    const float* W_eout = (const float*)d_in[23];
    const float* b_eout = (const float*)d_in[24];
    const float* W_node = (const float*)d_in[25];
    const float* b_node = (const float*)d_in[26];
    const float* W_fc   = (const float*)d_in[27];
    const float* b_fc   = (const float*)d_in[28];

    float* h_agg = (float*)d_ws;   // [N_DST,128] f32 = 2.56 MB

    hipMemsetAsync(h_agg, 0, (size_t)N_DST_N * H_N * sizeof(float), stream);

    edge_kernel<<<E_N, 256, 0, stream>>>(
        node_features, edge_features, seq_times, e_len, src_ids, dst_ids,
        W_ein, b_ein, Wqkv, bqkv, Wo, bo, ln1_g, ln1_b,
        W1, b1, W2, b2, ln2_g, ln2_b, W_eout, b_eout, h_agg);

    node_kernel<<<N_DST_N, 128, 0, stream>>>(
        node_features, layer_nid, subg_norm, h_agg,
        W_eout, b_eout, W_node, b_node, W_fc, b_fc, (float*)d_out);
}

// Round 2
// 1124.491 us; speedup vs baseline: 3.4549x; 3.4549x over previous
//
#include <hip/hip_runtime.h>

typedef __attribute__((ext_vector_type(8))) short bf16x8;
typedef __attribute__((ext_vector_type(4))) float f32x4;

#define E_N      32768
#define N_DST_N  5000
#define NCLS     10

// ---- workspace layout (bytes) ----
#define OFF_HAGG   0            // f32 [5000][128]  = 2,560,000 B
#define OFF_POOL   2560000      // bf16 [32768][128] = 8,388,608 B
#define OFF_WPACK  10948608     // bf16 packed fragments, 229376 elems

// packed-weight offsets in bf16x8 (8-elem) units
#define PK_QKV(l)  ((l) * 6144)
#define PK_WO(l)   (12288 + (l) * 2048)
#define PK_W1(l)   (16384 + (l) * 2048)
#define PK_W2(l)   (20480 + (l) * 2048)
#define PK_WEOUT   24576

__device__ __forceinline__ unsigned short f2bf(float f) {
    unsigned int u = __float_as_uint(f);
    u += 0x7fffu + ((u >> 16) & 1u);         // RNE
    return (unsigned short)(u >> 16);
}

// ---------------------------------------------------------------------------
// Pack all matmul weights into bf16 B-fragment order:
// dst[((t*(K/32)+kk)*64 + lane)*8 + j] = W[k][n],
//   n = t*16 + (lane&15), k = kk*32 + (lane>>4)*8 + j.
// ---------------------------------------------------------------------------
__global__ void pack_weights(const float* __restrict__ Wqkv,
                             const float* __restrict__ Wo,
                             const float* __restrict__ W1,
                             const float* __restrict__ W2,
                             const float* __restrict__ W_eout,
                             unsigned short* __restrict__ wpack) {
    int gid = blockIdx.x * 256 + threadIdx.x;
    if (gid >= 229376) return;
    int id = gid;
    const float* src; int K, N, li;
    if (id < 98304)       { src = Wqkv + (id / 49152) * 49152; li = id % 49152; K = 128; N = 384; }
    else if (id < 131072) { id -= 98304;  src = Wo + (id / 16384) * 16384; li = id % 16384; K = 128; N = 128; }
    else if (id < 163840) { id -= 131072; src = W1 + (id / 16384) * 16384; li = id % 16384; K = 128; N = 128; }
    else if (id < 196608) { id -= 163840; src = W2 + (id / 16384) * 16384; li = id % 16384; K = 128; N = 128; }
    else                  { li = id - 196608; src = W_eout; K = 256; N = 128; }
    int j = li & 7, lane = (li >> 3) & 63, rest = li >> 9;
    int ks = K >> 5;
    int kk = rest % ks, t = rest / ks;
    int k = kk * 32 + ((lane >> 4) << 3) + j;
    int n = t * 16 + (lane & 15);
    wpack[gid] = f2bf(src[k * N + n]);
}

// ---------------------------------------------------------------------------
// LayerNorm on a [16][128] fp32 LDS tile; writes fp32 back AND a bf16 mirror.
// 256 threads: 16 rows x 16 lanes, 8 columns each; shfl over 16-lane groups.
// ---------------------------------------------------------------------------
__device__ __forceinline__ void ln_rows(float (*ef)[132], unsigned short (*ab)[136],
                                        const float* __restrict__ g,
                                        const float* __restrict__ b, int tid) {
    int r = tid >> 4, jj = tid & 15;
    float vals[8];
#pragma unroll
    for (int m = 0; m < 8; ++m) vals[m] = ef[r][jj + 16 * m];
    float s = 0.f;
#pragma unroll
    for (int m = 0; m < 8; ++m) s += vals[m];
    s += __shfl_xor(s, 1); s += __shfl_xor(s, 2);
    s += __shfl_xor(s, 4); s += __shfl_xor(s, 8);
    float mu = s * (1.f / 128.f);
    float v = 0.f;
#pragma unroll
    for (int m = 0; m < 8; ++m) { float d = vals[m] - mu; v = fmaf(d, d, v); }
    v += __shfl_xor(v, 1); v += __shfl_xor(v, 2);
    v += __shfl_xor(v, 4); v += __shfl_xor(v, 8);
    float inv = rsqrtf(v * (1.f / 128.f) + 1e-5f);
#pragma unroll
    for (int m = 0; m < 8; ++m) {
        int col = jj + 16 * m;
        float y = (vals[m] - mu) * inv * g[col] + b[col];
        ef[r][col] = y;
        ab[r][col] = f2bf(y);
    }
}

// ---------------------------------------------------------------------------
// Edge mega-kernel: one block (4 waves) per edge. MFMA for QKV/proj/FF,
// vector fp32 attention + LN. Writes pooled edge embedding (bf16) to global.
// ---------------------------------------------------------------------------
__global__ __launch_bounds__(256, 4) void edge_kernel(
    const float* __restrict__ edge_features,   // [E,16,15]
    const float* __restrict__ seq_times,       // [E,16]
    const int*   __restrict__ e_len,
    const float* __restrict__ W_ein, const float* __restrict__ b_ein,
    const float* __restrict__ bqkv,  const float* __restrict__ bo,
    const float* __restrict__ ln1_g, const float* __restrict__ ln1_b,
    const float* __restrict__ b1,    const float* __restrict__ b2,
    const float* __restrict__ ln2_g, const float* __restrict__ ln2_b,
    const unsigned short* __restrict__ wpack,
    unsigned short* __restrict__ pooled)       // [E,128] bf16
{
    __shared__ float e_f32[16][132];                        // fp32 residual stream
    __shared__ __align__(16) unsigned short a_bf[16][136];  // bf16 A-operand mirror
    __shared__ float qkv_lds[16][392];                      // fp32 q|k|v for attention
    __shared__ float x_lds[16][16];

    const int tid  = threadIdx.x;
    const int eidx = blockIdx.x;
    const int lane = tid & 63;
    const int w    = tid >> 6;
    const int c16  = lane & 15;
    const int row4 = (lane >> 4) << 2;
    const int kblk = (lane >> 4) << 3;
    const int len  = e_len[eidx];

    // ---- stage input [16 tokens][16 feats] ----
    {
        int s = tid >> 4, i = tid & 15;
        x_lds[s][i] = (i < 15) ? edge_features[eidx * 240 + s * 15 + i]
                               : seq_times[eidx * 16 + s];
    }
    __syncthreads();

    // ---- embed: e = relu(x @ W_ein + b_ein)  (vector fp32, K=16) ----
    {
        int c = tid & 127, r0 = (tid >> 7) * 8;
        float acc[8];
#pragma unroll
        for (int r = 0; r < 8; ++r) acc[r] = 0.f;
#pragma unroll
        for (int i = 0; i < 16; ++i) {
            float wt = W_ein[i * 128 + c];
#pragma unroll
            for (int r = 0; r < 8; ++r)
                acc[r] = fmaf(x_lds[r0 + r][i], wt, acc[r]);
        }
        float bv = b_ein[c];
#pragma unroll
        for (int r = 0; r < 8; ++r) {
            float v = fmaxf(acc[r] + bv, 0.f);
            e_f32[r0 + r][c] = v;
            a_bf[r0 + r][c]  = f2bf(v);
        }
    }
    __syncthreads();

    const bf16x8* WP = (const bf16x8*)wpack;

    for (int l = 0; l < 2; ++l) {
        // ---- QKV: [16x128]@[128x384], wave w owns n-tiles w*6..w*6+5 ----
        {
            bf16x8 af[4];
#pragma unroll
            for (int kk = 0; kk < 4; ++kk)
                af[kk] = *(const bf16x8*)&a_bf[c16][kk * 32 + kblk];
            const bf16x8* B = WP + PK_QKV(l);
#pragma unroll
            for (int ti = 0; ti < 6; ++ti) {
                int t = w * 6 + ti;
                f32x4 acc = {0.f, 0.f, 0.f, 0.f};
#pragma unroll
                for (int kk = 0; kk < 4; ++kk)
                    acc = __builtin_amdgcn_mfma_f32_16x16x32_bf16(
                        af[kk], B[(t * 4 + kk) * 64 + lane], acc, 0, 0, 0);
                int col = t * 16 + c16;
                float bias = bqkv[l * 384 + col];
#pragma unroll
                for (int r = 0; r < 4; ++r)
                    qkv_lds[row4 + r][col] = acc[r] + bias;
            }
        }
        __syncthreads();

        // ---- attention: thread (head,q), fp32, fully unrolled+predicated ----
        if (tid < 128) {
            int hh = tid >> 4, qq = tid & 15, hb = hh * 16;
            float qv[16];
#pragma unroll
            for (int d = 0; d < 16; ++d) qv[d] = qkv_lds[qq][hb + d];
            float sc[16];
            float mx = -1e30f;
#pragma unroll
            for (int kk = 0; kk < 16; ++kk) {
                float s = 0.f;
#pragma unroll
                for (int d = 0; d < 16; ++d)
                    s = fmaf(qv[d], qkv_lds[kk][128 + hb + d], s);
                s *= 0.25f;
                sc[kk] = s;
                mx = fmaxf(mx, (kk < len) ? s : -1e30f);
            }
            float sum = 0.f;
#pragma unroll
            for (int kk = 0; kk < 16; ++kk) {
                float p = (kk < len) ? __expf(sc[kk] - mx) : 0.f;
                sc[kk] = p;
                sum += p;
            }
            float inv = 1.f / sum;
            float ctx[16];
#pragma unroll
            for (int d = 0; d < 16; ++d) ctx[d] = 0.f;
#pragma unroll
            for (int kk = 0; kk < 16; ++kk) {
                float p = sc[kk] * inv;
#pragma unroll
                for (int d = 0; d < 16; ++d)
                    ctx[d] = fmaf(p, qkv_lds[kk][256 + hb + d], ctx[d]);
            }
#pragma unroll
            for (int d = 0; d < 16; ++d) a_bf[qq][hb + d] = f2bf(ctx[d]);
        }
        __syncthreads();

        // ---- proj + residual: e_f32 += ctx @ Wo + bo ----
        {
            bf16x8 af[4];
#pragma unroll
            for (int kk = 0; kk < 4; ++kk)
                af[kk] = *(const bf16x8*)&a_bf[c16][kk * 32 + kblk];
            const bf16x8* B = WP + PK_WO(l);
#pragma unroll
            for (int ti = 0; ti < 2; ++ti) {
                int t = w * 2 + ti;
                f32x4 acc = {0.f, 0.f, 0.f, 0.f};
#pragma unroll
                for (int kk = 0; kk < 4; ++kk)
                    acc = __builtin_amdgcn_mfma_f32_16x16x32_bf16(
                        af[kk], B[(t * 4 + kk) * 64 + lane], acc, 0, 0, 0);
                int col = t * 16 + c16;
                float bias = bo[l * 128 + col];
#pragma unroll
                for (int r = 0; r < 4; ++r)
                    e_f32[row4 + r][col] += acc[r] + bias;
            }
        }
        __syncthreads();

        ln_rows(e_f32, a_bf, ln1_g + l * 128, ln1_b + l * 128, tid);
        __syncthreads();

        // ---- FF1: ffh = relu(e @ W1 + b1) -> a_bf (barrier between read+write) ----
        {
            bf16x8 af[4];
#pragma unroll
            for (int kk = 0; kk < 4; ++kk)
                af[kk] = *(const bf16x8*)&a_bf[c16][kk * 32 + kblk];
            const bf16x8* B = WP + PK_W1(l);
            f32x4 acc2[2];
#pragma unroll
            for (int ti = 0; ti < 2; ++ti) {
                int t = w * 2 + ti;
                f32x4 acc = {0.f, 0.f, 0.f, 0.f};
#pragma unroll
                for (int kk = 0; kk < 4; ++kk)
                    acc = __builtin_amdgcn_mfma_f32_16x16x32_bf16(
                        af[kk], B[(t * 4 + kk) * 64 + lane], acc, 0, 0, 0);
                acc2[ti] = acc;
            }
            __syncthreads();   // all waves' A-frag reads done before overwrite
#pragma unroll
            for (int ti = 0; ti < 2; ++ti) {
                int t = w * 2 + ti;
                int col = t * 16 + c16;
                float bias = b1[l * 128 + col];
#pragma unroll
                for (int r = 0; r < 4; ++r)
                    a_bf[row4 + r][col] = f2bf(fmaxf(acc2[ti][r] + bias, 0.f));
            }
        }
        __syncthreads();

        // ---- FF2 + residual: e_f32 += ffh @ W2 + b2 ----
        {
            bf16x8 af[4];
#pragma unroll
            for (int kk = 0; kk < 4; ++kk)
                af[kk] = *(const bf16x8*)&a_bf[c16][kk * 32 + kblk];
            const bf16x8* B = WP + PK_W2(l);
#pragma unroll
            for (int ti = 0; ti < 2; ++ti) {
                int t = w * 2 + ti;
                f32x4 acc = {0.f, 0.f, 0.f, 0.f};
#pragma unroll
                for (int kk = 0; kk < 4; ++kk)
                    acc = __builtin_amdgcn_mfma_f32_16x16x32_bf16(
                        af[kk], B[(t * 4 + kk) * 64 + lane], acc, 0, 0, 0);
                int col = t * 16 + c16;
                float bias = b2[l * 128 + col];
#pragma unroll
                for (int r = 0; r < 4; ++r)
                    e_f32[row4 + r][col] += acc[r] + bias;
            }
        }
        __syncthreads();

        ln_rows(e_f32, a_bf, ln2_g + l * 128, ln2_b + l * 128, tid);
        __syncthreads();
    }

    // ---- masked mean pool -> pooled[eidx] (bf16) ----
    if (tid < 128) {
        float s = 0.f;
#pragma unroll
        for (int ss = 0; ss < 16; ++ss)
            s += (ss < len) ? e_f32[ss][tid] : 0.f;
        pooled[eidx * 128 + tid] = f2bf(s / (float)len);
    }
}

// ---------------------------------------------------------------------------
// Edge-out: m = relu(concat(h[src], pooled) @ W_eout + b_eout), 16 edges/block
// via MFMA (M=16 edges, K=256), atomic scatter into h_agg.
// ---------------------------------------------------------------------------
__global__ __launch_bounds__(256) void edge_out_kernel(
    const float* __restrict__ node_features,
    const int* __restrict__ src_ids, const int* __restrict__ dst_ids,
    const unsigned short* __restrict__ pooled,
    const unsigned short* __restrict__ wpack,
    const float* __restrict__ b_eout,
    float* __restrict__ h_agg)
{
    __shared__ __align__(16) unsigned short a2[16][264];
    __shared__ int dst_s[16];
    const int tid = threadIdx.x, lane = tid & 63, w = tid >> 6;
    const int e0 = blockIdx.x * 16;

    {
        int r = tid >> 4, cm = tid & 15;
        int e = e0 + r;
        int src = src_ids[e];
#pragma unroll
        for (int m = 0; m < 8; ++m) {
            int col = cm + 16 * m;
            a2[r][col] = f2bf(node_features[src * 128 + col]);
        }
#pragma unroll
        for (int m = 0; m < 8; ++m) {
            int col = cm + 16 * m;
            a2[r][128 + col] = pooled[e * 128 + col];
        }
        if (tid < 16) dst_s[tid] = dst_ids[e0 + tid];
    }
    __syncthreads();

    const int c16 = lane & 15, row4 = (lane >> 4) << 2, kblk = (lane >> 4) << 3;
    bf16x8 af[8];
#pragma unroll
    for (int kk = 0; kk < 8; ++kk)
        af[kk] = *(const bf16x8*)&a2[c16][kk * 32 + kblk];
    const bf16x8* B = (const bf16x8*)wpack + PK_WEOUT;
#pragma unroll
    for (int ti = 0; ti < 2; ++ti) {
        int t = w * 2 + ti;
        f32x4 acc = {0.f, 0.f, 0.f, 0.f};
#pragma unroll
        for (int kk = 0; kk < 8; ++kk)
            acc = __builtin_amdgcn_mfma_f32_16x16x32_bf16(
                af[kk], B[(t * 8 + kk) * 64 + lane], acc, 0, 0, 0);
        int col = t * 16 + c16;
        float bias = b_eout[col];
#pragma unroll
        for (int r = 0; r < 4; ++r) {
            int row = row4 + r;
            float v = fmaxf(acc[r] + bias, 0.f);
            atomicAdd(&h_agg[dst_s[row] * 128 + col], v);
        }
    }
}

// ---------------------------------------------------------------------------
// Node update: one block (128 threads) per destination node.
// ---------------------------------------------------------------------------
__global__ __launch_bounds__(128) void node_kernel(
    const float* __restrict__ node_features,
    const int*   __restrict__ layer_nid,
    const float* __restrict__ subg_norm,
    const float* __restrict__ h_agg,
    const float* __restrict__ W_eout, const float* __restrict__ b_eout,
    const float* __restrict__ W_node, const float* __restrict__ b_node,
    const float* __restrict__ W_fc,   const float* __restrict__ b_fc,
    float* __restrict__ out)
{
    __shared__ float sh[128];
    __shared__ float hh[128];
    __shared__ float z[128];

    const int n   = blockIdx.x;
    const int tid = threadIdx.x;
    const int nid = layer_nid[n];
    const float norm = subg_norm[n];

    sh[tid] = node_features[nid * 128 + tid];
    __syncthreads();

    float acc = 0.f;
#pragma unroll 4
    for (int k = 0; k < 128; ++k)
        acc = fmaf(sh[k], W_eout[k * 128 + tid], acc);
    acc += b_eout[tid];
    hh[tid] = (h_agg[n * 128 + tid] - acc) * norm;
    __syncthreads();

    float za = 0.f;
#pragma unroll 4
    for (int k = 0; k < 128; ++k)
        za = fmaf(sh[k], W_node[k * 128 + tid], za);
#pragma unroll 4
    for (int k = 0; k < 128; ++k)
        za = fmaf(hh[k], W_node[(128 + k) * 128 + tid], za);
    za += b_node[tid];
    z[tid] = fmaxf(za, 0.f);
    __syncthreads();

    if (tid < NCLS) {
        float o = 0.f;
#pragma unroll 4
        for (int k = 0; k < 128; ++k)
            o = fmaf(z[k], W_fc[k * NCLS + tid], o);
        out[n * NCLS + tid] = o + b_fc[tid];
    }
}

// ---------------------------------------------------------------------------

extern "C" void kernel_launch(void* const* d_in, const int* in_sizes, int n_in,
                              void* d_out, int out_size, void* d_ws, size_t ws_size,
                              hipStream_t stream) {
    const float* node_features = (const float*)d_in[0];
    const float* edge_features = (const float*)d_in[1];
    const float* seq_times     = (const float*)d_in[2];
    const int*   e_len         = (const int*)d_in[3];
    // d_in[4] = e_mask (recomputed from e_len)
    const int*   src_ids       = (const int*)d_in[5];
    const int*   dst_ids       = (const int*)d_in[6];
    const int*   layer_nid     = (const int*)d_in[7];
    const float* subg_norm     = (const float*)d_in[8];
    const float* W_ein  = (const float*)d_in[9];
    const float* b_ein  = (const float*)d_in[10];
    const float* Wqkv   = (const float*)d_in[11];
    const float* bqkv   = (const float*)d_in[12];
    const float* Wo     = (const float*)d_in[13];
    const float* bo     = (const float*)d_in[14];
    const float* ln1_g  = (const float*)d_in[15];
    const float* ln1_b  = (const float*)d_in[16];
    const float* W1     = (const float*)d_in[17];
    const float* b1     = (const float*)d_in[18];
    const float* W2     = (const float*)d_in[19];
    const float* b2     = (const float*)d_in[20];
    const float* ln2_g  = (const float*)d_in[21];
    const float* ln2_b  = (const float*)d_in[22];
    const float* W_eout = (const float*)d_in[23];
    const float* b_eout = (const float*)d_in[24];
    const float* W_node = (const float*)d_in[25];
    const float* b_node = (const float*)d_in[26];
    const float* W_fc   = (const float*)d_in[27];
    const float* b_fc   = (const float*)d_in[28];

    float*          h_agg  = (float*)((char*)d_ws + OFF_HAGG);
    unsigned short* pooled = (unsigned short*)((char*)d_ws + OFF_POOL);
    unsigned short* wpack  = (unsigned short*)((char*)d_ws + OFF_WPACK);

    pack_weights<<<896, 256, 0, stream>>>(Wqkv, Wo, W1, W2, W_eout, wpack);
    hipMemsetAsync(h_agg, 0, (size_t)N_DST_N * 128 * sizeof(float), stream);

    edge_kernel<<<E_N, 256, 0, stream>>>(
        edge_features, seq_times, e_len,
        W_ein, b_ein, bqkv, bo, ln1_g, ln1_b, b1, b2, ln2_g, ln2_b,
        wpack, pooled);

    edge_out_kernel<<<E_N / 16, 256, 0, stream>>>(
        node_features, src_ids, dst_ids, pooled, wpack, b_eout, h_agg);

    node_kernel<<<N_DST_N, 128, 0, stream>>>(
        node_features, layer_nid, subg_norm, h_agg,
        W_eout, b_eout, W_node, b_node, W_fc, b_fc, (float*)d_out);
}

// Round 3
// 888.534 us; speedup vs baseline: 4.3724x; 1.2656x over previous
//
#include <hip/hip_runtime.h>

typedef __attribute__((ext_vector_type(8))) short bf16x8;
typedef __attribute__((ext_vector_type(4))) float f32x4;

#define E_N      32768
#define N_DST_N  5000
#define NCLS     10

// ---- workspace layout (bytes) ----
#define OFF_HAGG   0            // f32 [5000][128]  = 2,560,000 B
#define OFF_POOL   2560000      // bf16 [32768][128] = 8,388,608 B
#define OFF_WPACK  10948608     // bf16 packed fragments, 229376 elems

// packed-weight offsets in bf16x8 (8-elem) units
#define PK_QKV(l)  ((l) * 6144)
#define PK_WO(l)   (12288 + (l) * 2048)
#define PK_W1(l)   (16384 + (l) * 2048)
#define PK_W2(l)   (20480 + (l) * 2048)
#define PK_WEOUT   24576

// LDS pitches (elements)
#define QP 408     // qkv_bf pitch (bf16): Q@0, K@136, V@272
#define AP 136     // a_bf pitch (bf16)
#define EP 132     // e_f32 pitch (f32)

__device__ __forceinline__ unsigned short f2bf(float f) {
    unsigned int u = __float_as_uint(f);
    u += 0x7fffu + ((u >> 16) & 1u);         // RNE
    return (unsigned short)(u >> 16);
}
__device__ __forceinline__ float bf2f(unsigned short u) {
    return __uint_as_float(((unsigned int)u) << 16);
}

// ---------------------------------------------------------------------------
// Pack all matmul weights into bf16 B-fragment order:
// dst[((t*(K/32)+kk)*64 + lane)*8 + j] = W[k][n],
//   n = t*16 + (lane&15), k = kk*32 + (lane>>4)*8 + j.
// ---------------------------------------------------------------------------
__global__ void pack_weights(const float* __restrict__ Wqkv,
                             const float* __restrict__ Wo,
                             const float* __restrict__ W1,
                             const float* __restrict__ W2,
                             const float* __restrict__ W_eout,
                             unsigned short* __restrict__ wpack) {
    int gid = blockIdx.x * 256 + threadIdx.x;
    if (gid >= 229376) return;
    int id = gid;
    const float* src; int K, N, li;
    if (id < 98304)       { src = Wqkv + (id / 49152) * 49152; li = id % 49152; K = 128; N = 384; }
    else if (id < 131072) { id -= 98304;  src = Wo + (id / 16384) * 16384; li = id % 16384; K = 128; N = 128; }
    else if (id < 163840) { id -= 131072; src = W1 + (id / 16384) * 16384; li = id % 16384; K = 128; N = 128; }
    else if (id < 196608) { id -= 163840; src = W2 + (id / 16384) * 16384; li = id % 16384; K = 128; N = 128; }
    else                  { li = id - 196608; src = W_eout; K = 256; N = 128; }
    int j = li & 7, lane = (li >> 3) & 63, rest = li >> 9;
    int ks = K >> 5;
    int kk = rest % ks, t = rest / ks;
    int k = kk * 32 + ((lane >> 4) << 3) + j;
    int n = t * 16 + (lane & 15);
    wpack[gid] = f2bf(src[k * N + n]);
}

// ---------------------------------------------------------------------------
// Edge mega-kernel: one block (4 waves) per TWO edges (32 token rows).
// MFMA (B-frags reused across both edges) for QKV/proj/FF; fp32 vector
// attention + LN. Residual stream fp32 in LDS; qkv + A-operand bf16 in LDS.
// ---------------------------------------------------------------------------
__global__ __launch_bounds__(256, 3) void edge_kernel(
    const float* __restrict__ edge_features,   // [E,16,15]
    const float* __restrict__ seq_times,       // [E,16]
    const int*   __restrict__ e_len,
    const float* __restrict__ W_ein, const float* __restrict__ b_ein,
    const float* __restrict__ bqkv,  const float* __restrict__ bo,
    const float* __restrict__ ln1_g, const float* __restrict__ ln1_b,
    const float* __restrict__ b1,    const float* __restrict__ b2,
    const float* __restrict__ ln2_g, const float* __restrict__ ln2_b,
    const unsigned short* __restrict__ wpack,
    unsigned short* __restrict__ pooled)       // [E,128] bf16
{
    __shared__ float e_f32[32][EP];                          // fp32 residual
    __shared__ __align__(16) unsigned short a_bf[32][AP];    // bf16 A-operand
    __shared__ __align__(16) unsigned short qkv_bf[32][QP];  // bf16 q|k|v
    __shared__ float x_lds[32][16];

    const int tid  = threadIdx.x;
    const int e0   = blockIdx.x * 2;
    const int lane = tid & 63;
    const int w    = tid >> 6;
    const int c16  = lane & 15;
    const int row4 = (lane >> 4) << 2;
    const int kblk = (lane >> 4) << 3;
    const int len0 = e_len[e0];
    const int len1 = e_len[e0 + 1];

    // ---- stage inputs [2 edges][16 tokens][16 feats] ----
#pragma unroll
    for (int idx = tid; idx < 512; idx += 256) {
        int e = idx >> 8, s = (idx >> 4) & 15, i = idx & 15;
        x_lds[e * 16 + s][i] = (i < 15) ? edge_features[(e0 + e) * 240 + s * 15 + i]
                                        : seq_times[(e0 + e) * 16 + s];
    }
    __syncthreads();

    // ---- embed: e = relu(x @ W_ein + b_ein) (vector fp32, K=16) ----
    {
        int c = tid & 127, er = (tid >> 7) * 16;
        float acc[16];
#pragma unroll
        for (int r = 0; r < 16; ++r) acc[r] = 0.f;
#pragma unroll
        for (int i = 0; i < 16; ++i) {
            float wt = W_ein[i * 128 + c];
#pragma unroll
            for (int r = 0; r < 16; ++r)
                acc[r] = fmaf(x_lds[er + r][i], wt, acc[r]);
        }
        float bv = b_ein[c];
#pragma unroll
        for (int r = 0; r < 16; ++r) {
            float v = fmaxf(acc[r] + bv, 0.f);
            e_f32[er + r][c] = v;
            a_bf[er + r][c]  = f2bf(v);
        }
    }
    __syncthreads();

    const bf16x8* WP = (const bf16x8*)wpack;

    for (int l = 0; l < 2; ++l) {
        // ---- QKV: [32x128]@[128x384]; wave w owns n-tiles w*6..w*6+5,
        //      processed in 2 chunks of 3 (register pressure) ----
        {
            bf16x8 af[2][4];
#pragma unroll
            for (int rt = 0; rt < 2; ++rt)
#pragma unroll
                for (int kk = 0; kk < 4; ++kk)
                    af[rt][kk] = *(const bf16x8*)&a_bf[rt * 16 + c16][kk * 32 + kblk];
            const bf16x8* B = WP + PK_QKV(l);
#pragma unroll
            for (int half = 0; half < 2; ++half) {
                bf16x8 bq[3][4];
#pragma unroll
                for (int ti = 0; ti < 3; ++ti)
#pragma unroll
                    for (int kk = 0; kk < 4; ++kk)
                        bq[ti][kk] = B[((w * 6 + half * 3 + ti) * 4 + kk) * 64 + lane];
#pragma unroll
                for (int ti = 0; ti < 3; ++ti) {
                    int t = w * 6 + half * 3 + ti;
                    int seg = t >> 3;                       // 0=q 1=k 2=v
                    int ldcol = seg * 136 + (t & 7) * 16 + c16;
                    float bias = bqkv[l * 384 + t * 16 + c16];
#pragma unroll
                    for (int rt = 0; rt < 2; ++rt) {
                        f32x4 acc = {0.f, 0.f, 0.f, 0.f};
#pragma unroll
                        for (int kk = 0; kk < 4; ++kk)
                            acc = __builtin_amdgcn_mfma_f32_16x16x32_bf16(
                                af[rt][kk], bq[ti][kk], acc, 0, 0, 0);
#pragma unroll
                        for (int r = 0; r < 4; ++r)
                            qkv_bf[rt * 16 + row4 + r][ldcol] = f2bf(acc[r] + bias);
                    }
                }
            }
        }
        __syncthreads();

        // ---- attention: 256 threads = 2 edges x 8 heads x 16 q-rows ----
        {
            int e  = tid >> 7;
            int hb = ((tid >> 4) & 7) * 16;
            int qq = tid & 15;
            int er = e * 16;
            int len = e ? len1 : len0;
            float qv[16];
            {
                bf16x8 v0 = *(const bf16x8*)&qkv_bf[er + qq][hb];
                bf16x8 v1 = *(const bf16x8*)&qkv_bf[er + qq][hb + 8];
#pragma unroll
                for (int j = 0; j < 8; ++j) {
                    qv[j]     = bf2f((unsigned short)v0[j]);
                    qv[8 + j] = bf2f((unsigned short)v1[j]);
                }
            }
            float sc[16];
            float mx = -1e30f;
#pragma unroll
            for (int kk = 0; kk < 16; ++kk) {
                bf16x8 k0 = *(const bf16x8*)&qkv_bf[er + kk][136 + hb];
                bf16x8 k1 = *(const bf16x8*)&qkv_bf[er + kk][136 + hb + 8];
                float s = 0.f;
#pragma unroll
                for (int j = 0; j < 8; ++j) {
                    s = fmaf(qv[j],     bf2f((unsigned short)k0[j]), s);
                    s = fmaf(qv[8 + j], bf2f((unsigned short)k1[j]), s);
                }
                s *= 0.25f;
                sc[kk] = s;
                mx = fmaxf(mx, (kk < len) ? s : -1e30f);
            }
            float sum = 0.f;
#pragma unroll
            for (int kk = 0; kk < 16; ++kk) {
                float p = (kk < len) ? __expf(sc[kk] - mx) : 0.f;
                sc[kk] = p;
                sum += p;
            }
            float inv = 1.f / sum;
            float ctx[16];
#pragma unroll
            for (int d = 0; d < 16; ++d) ctx[d] = 0.f;
#pragma unroll
            for (int kk = 0; kk < 16; ++kk) {
                float p = sc[kk] * inv;
                bf16x8 v0 = *(const bf16x8*)&qkv_bf[er + kk][272 + hb];
                bf16x8 v1 = *(const bf16x8*)&qkv_bf[er + kk][272 + hb + 8];
#pragma unroll
                for (int j = 0; j < 8; ++j) {
                    ctx[j]     = fmaf(p, bf2f((unsigned short)v0[j]), ctx[j]);
                    ctx[8 + j] = fmaf(p, bf2f((unsigned short)v1[j]), ctx[8 + j]);
                }
            }
            bf16x8 o0, o1;
#pragma unroll
            for (int j = 0; j < 8; ++j) {
                o0[j] = (short)f2bf(ctx[j]);
                o1[j] = (short)f2bf(ctx[8 + j]);
            }
            __syncthreads();    // ensure all QKV-phase a_bf reads... (none) + ordering
            *(bf16x8*)&a_bf[er + qq][hb]     = o0;
            *(bf16x8*)&a_bf[er + qq][hb + 8] = o1;
        }
        __syncthreads();

        // ---- proj + residual: e_f32 += ctx @ Wo + bo ----
        {
            bf16x8 af[2][4];
#pragma unroll
            for (int rt = 0; rt < 2; ++rt)
#pragma unroll
                for (int kk = 0; kk < 4; ++kk)
                    af[rt][kk] = *(const bf16x8*)&a_bf[rt * 16 + c16][kk * 32 + kblk];
            const bf16x8* B = WP + PK_WO(l);
            bf16x8 bw[2][4];
#pragma unroll
            for (int ti = 0; ti < 2; ++ti)
#pragma unroll
                for (int kk = 0; kk < 4; ++kk)
                    bw[ti][kk] = B[((w * 2 + ti) * 4 + kk) * 64 + lane];
#pragma unroll
            for (int ti = 0; ti < 2; ++ti) {
                int col = (w * 2 + ti) * 16 + c16;
                float bias = bo[l * 128 + col];
#pragma unroll
                for (int rt = 0; rt < 2; ++rt) {
                    f32x4 acc = {0.f, 0.f, 0.f, 0.f};
#pragma unroll
                    for (int kk = 0; kk < 4; ++kk)
                        acc = __builtin_amdgcn_mfma_f32_16x16x32_bf16(
                            af[rt][kk], bw[ti][kk], acc, 0, 0, 0);
#pragma unroll
                    for (int r = 0; r < 4; ++r)
                        e_f32[rt * 16 + row4 + r][col] += acc[r] + bias;
                }
            }
        }
        __syncthreads();

        // ---- LN1: 32 rows x 8 lanes, 16 cols each ----
        {
            const float* g = ln1_g + l * 128;
            const float* b = ln1_b + l * 128;
            int r = tid >> 3, j = tid & 7;
            float vals[16];
#pragma unroll
            for (int m = 0; m < 16; ++m) vals[m] = e_f32[r][j + 8 * m];
            float s = 0.f;
#pragma unroll
            for (int m = 0; m < 16; ++m) s += vals[m];
            s += __shfl_xor(s, 1); s += __shfl_xor(s, 2); s += __shfl_xor(s, 4);
            float mu = s * (1.f / 128.f);
            float v = 0.f;
#pragma unroll
            for (int m = 0; m < 16; ++m) { float d = vals[m] - mu; v = fmaf(d, d, v); }
            v += __shfl_xor(v, 1); v += __shfl_xor(v, 2); v += __shfl_xor(v, 4);
            float inv = rsqrtf(v * (1.f / 128.f) + 1e-5f);
#pragma unroll
            for (int m = 0; m < 16; ++m) {
                int col = j + 8 * m;
                float y = (vals[m] - mu) * inv * g[col] + b[col];
                e_f32[r][col] = y;
                a_bf[r][col]  = f2bf(y);
            }
        }
        __syncthreads();

        // ---- FF1: ffh = relu(e @ W1 + b1) -> a_bf ----
        {
            bf16x8 af[2][4];
#pragma unroll
            for (int rt = 0; rt < 2; ++rt)
#pragma unroll
                for (int kk = 0; kk < 4; ++kk)
                    af[rt][kk] = *(const bf16x8*)&a_bf[rt * 16 + c16][kk * 32 + kblk];
            const bf16x8* B = WP + PK_W1(l);
            bf16x8 bw[2][4];
#pragma unroll
            for (int ti = 0; ti < 2; ++ti)
#pragma unroll
                for (int kk = 0; kk < 4; ++kk)
                    bw[ti][kk] = B[((w * 2 + ti) * 4 + kk) * 64 + lane];
            f32x4 acc2[2][2];
#pragma unroll
            for (int ti = 0; ti < 2; ++ti)
#pragma unroll
                for (int rt = 0; rt < 2; ++rt) {
                    f32x4 acc = {0.f, 0.f, 0.f, 0.f};
#pragma unroll
                    for (int kk = 0; kk < 4; ++kk)
                        acc = __builtin_amdgcn_mfma_f32_16x16x32_bf16(
                            af[rt][kk], bw[ti][kk], acc, 0, 0, 0);
                    acc2[ti][rt] = acc;
                }
            __syncthreads();   // all waves done reading a_bf before overwrite
#pragma unroll
            for (int ti = 0; ti < 2; ++ti) {
                int col = (w * 2 + ti) * 16 + c16;
                float bias = b1[l * 128 + col];
#pragma unroll
                for (int rt = 0; rt < 2; ++rt)
#pragma unroll
                    for (int r = 0; r < 4; ++r)
                        a_bf[rt * 16 + row4 + r][col] =
                            f2bf(fmaxf(acc2[ti][rt][r] + bias, 0.f));
            }
        }
        __syncthreads();

        // ---- FF2 + residual: e_f32 += ffh @ W2 + b2 ----
        {
            bf16x8 af[2][4];
#pragma unroll
            for (int rt = 0; rt < 2; ++rt)
#pragma unroll
                for (int kk = 0; kk < 4; ++kk)
                    af[rt][kk] = *(const bf16x8*)&a_bf[rt * 16 + c16][kk * 32 + kblk];
            const bf16x8* B = WP + PK_W2(l);
            bf16x8 bw[2][4];
#pragma unroll
            for (int ti = 0; ti < 2; ++ti)
#pragma unroll
                for (int kk = 0; kk < 4; ++kk)
                    bw[ti][kk] = B[((w * 2 + ti) * 4 + kk) * 64 + lane];
#pragma unroll
            for (int ti = 0; ti < 2; ++ti) {
                int col = (w * 2 + ti) * 16 + c16;
                float bias = b2[l * 128 + col];
#pragma unroll
                for (int rt = 0; rt < 2; ++rt) {
                    f32x4 acc = {0.f, 0.f, 0.f, 0.f};
#pragma unroll
                    for (int kk = 0; kk < 4; ++kk)
                        acc = __builtin_amdgcn_mfma_f32_16x16x32_bf16(
                            af[rt][kk], bw[ti][kk], acc, 0, 0, 0);
#pragma unroll
                    for (int r = 0; r < 4; ++r)
                        e_f32[rt * 16 + row4 + r][col] += acc[r] + bias;
                }
            }
        }
        __syncthreads();

        // ---- LN2 ----
        {
            const float* g = ln2_g + l * 128;
            const float* b = ln2_b + l * 128;
            int r = tid >> 3, j = tid & 7;
            float vals[16];
#pragma unroll
            for (int m = 0; m < 16; ++m) vals[m] = e_f32[r][j + 8 * m];
            float s = 0.f;
#pragma unroll
            for (int m = 0; m < 16; ++m) s += vals[m];
            s += __shfl_xor(s, 1); s += __shfl_xor(s, 2); s += __shfl_xor(s, 4);
            float mu = s * (1.f / 128.f);
            float v = 0.f;
#pragma unroll
            for (int m = 0; m < 16; ++m) { float d = vals[m] - mu; v = fmaf(d, d, v); }
            v += __shfl_xor(v, 1); v += __shfl_xor(v, 2); v += __shfl_xor(v, 4);
            float inv = rsqrtf(v * (1.f / 128.f) + 1e-5f);
#pragma unroll
            for (int m = 0; m < 16; ++m) {
                int col = j + 8 * m;
                float y = (vals[m] - mu) * inv * g[col] + b[col];
                e_f32[r][col] = y;
                a_bf[r][col]  = f2bf(y);
            }
        }
        __syncthreads();
    }

    // ---- masked mean pool -> pooled (bf16) ----
    {
        int e = tid >> 7, c = tid & 127;
        int len = e ? len1 : len0;
        float s = 0.f;
#pragma unroll
        for (int ss = 0; ss < 16; ++ss)
            s += (ss < len) ? e_f32[e * 16 + ss][c] : 0.f;
        pooled[(e0 + e) * 128 + c] = f2bf(s / (float)len);
    }
}

// ---------------------------------------------------------------------------
// Edge-out: m = relu(concat(h[src], pooled) @ W_eout + b_eout), 16 edges/block
// via MFMA (M=16 edges, K=256), atomic scatter into h_agg.
// ---------------------------------------------------------------------------
__global__ __launch_bounds__(256) void edge_out_kernel(
    const float* __restrict__ node_features,
    const int* __restrict__ src_ids, const int* __restrict__ dst_ids,
    const unsigned short* __restrict__ pooled,
    const unsigned short* __restrict__ wpack,
    const float* __restrict__ b_eout,
    float* __restrict__ h_agg)
{
    __shared__ __align__(16) unsigned short a2[16][264];
    __shared__ int dst_s[16];
    const int tid = threadIdx.x, lane = tid & 63, w = tid >> 6;
    const int e0 = blockIdx.x * 16;

    {
        int r = tid >> 4, cm = tid & 15;
        int e = e0 + r;
        int src = src_ids[e];
#pragma unroll
        for (int m = 0; m < 8; ++m) {
            int col = cm + 16 * m;
            a2[r][col] = f2bf(node_features[src * 128 + col]);
        }
#pragma unroll
        for (int m = 0; m < 8; ++m) {
            int col = cm + 16 * m;
            a2[r][128 + col] = pooled[e * 128 + col];
        }
        if (tid < 16) dst_s[tid] = dst_ids[e0 + tid];
    }
    __syncthreads();

    const int c16 = lane & 15, row4 = (lane >> 4) << 2, kblk = (lane >> 4) << 3;
    bf16x8 af[8];
#pragma unroll
    for (int kk = 0; kk < 8; ++kk)
        af[kk] = *(const bf16x8*)&a2[c16][kk * 32 + kblk];
    const bf16x8* B = (const bf16x8*)wpack + PK_WEOUT;
#pragma unroll
    for (int ti = 0; ti < 2; ++ti) {
        int t = w * 2 + ti;
        f32x4 acc = {0.f, 0.f, 0.f, 0.f};
#pragma unroll
        for (int kk = 0; kk < 8; ++kk)
            acc = __builtin_amdgcn_mfma_f32_16x16x32_bf16(
                af[kk], B[(t * 8 + kk) * 64 + lane], acc, 0, 0, 0);
        int col = t * 16 + c16;
        float bias = b_eout[col];
#pragma unroll
        for (int r = 0; r < 4; ++r) {
            int row = row4 + r;
            float v = fmaxf(acc[r] + bias, 0.f);
            atomicAdd(&h_agg[dst_s[row] * 128 + col], v);
        }
    }
}

// ---------------------------------------------------------------------------
// Node update: one block (128 threads) per destination node.
// ---------------------------------------------------------------------------
__global__ __launch_bounds__(128) void node_kernel(
    const float* __restrict__ node_features,
    const int*   __restrict__ layer_nid,
    const float* __restrict__ subg_norm,
    const float* __restrict__ h_agg,
    const float* __restrict__ W_eout, const float* __restrict__ b_eout,
    const float* __restrict__ W_node, const float* __restrict__ b_node,
    const float* __restrict__ W_fc,   const float* __restrict__ b_fc,
    float* __restrict__ out)
{
    __shared__ float sh[128];
    __shared__ float hh[128];
    __shared__ float z[128];

    const int n   = blockIdx.x;
    const int tid = threadIdx.x;
    const int nid = layer_nid[n];
    const float norm = subg_norm[n];

    sh[tid] = node_features[nid * 128 + tid];
    __syncthreads();

    float acc = 0.f;
#pragma unroll 4
    for (int k = 0; k < 128; ++k)
        acc = fmaf(sh[k], W_eout[k * 128 + tid], acc);
    acc += b_eout[tid];
    hh[tid] = (h_agg[n * 128 + tid] - acc) * norm;
    __syncthreads();

    float za = 0.f;
#pragma unroll 4
    for (int k = 0; k < 128; ++k)
        za = fmaf(sh[k], W_node[k * 128 + tid], za);
#pragma unroll 4
    for (int k = 0; k < 128; ++k)
        za = fmaf(hh[k], W_node[(128 + k) * 128 + tid], za);
    za += b_node[tid];
    z[tid] = fmaxf(za, 0.f);
    __syncthreads();

    if (tid < NCLS) {
        float o = 0.f;
#pragma unroll 4
        for (int k = 0; k < 128; ++k)
            o = fmaf(z[k], W_fc[k * NCLS + tid], o);
        out[n * NCLS + tid] = o + b_fc[tid];
    }
}

// ---------------------------------------------------------------------------

extern "C" void kernel_launch(void* const* d_in, const int* in_sizes, int n_in,
                              void* d_out, int out_size, void* d_ws, size_t ws_size,
                              hipStream_t stream) {
    const float* node_features = (const float*)d_in[0];
    const float* edge_features = (const float*)d_in[1];
    const float* seq_times     = (const float*)d_in[2];
    const int*   e_len         = (const int*)d_in[3];
    // d_in[4] = e_mask (recomputed from e_len)
    const int*   src_ids       = (const int*)d_in[5];
    const int*   dst_ids       = (const int*)d_in[6];
    const int*   layer_nid     = (const int*)d_in[7];
    const float* subg_norm     = (const float*)d_in[8];
    const float* W_ein  = (const float*)d_in[9];
    const float* b_ein  = (const float*)d_in[10];
    const float* Wqkv   = (const float*)d_in[11];
    const float* bqkv   = (const float*)d_in[12];
    const float* Wo     = (const float*)d_in[13];
    const float* bo     = (const float*)d_in[14];
    const float* ln1_g  = (const float*)d_in[15];
    const float* ln1_b  = (const float*)d_in[16];
    const float* W1     = (const float*)d_in[17];
    const float* b1     = (const float*)d_in[18];
    const float* W2     = (const float*)d_in[19];
    const float* b2     = (const float*)d_in[20];
    const float* ln2_g  = (const float*)d_in[21];
    const float* ln2_b  = (const float*)d_in[22];
    const float* W_eout = (const float*)d_in[23];
    const float* b_eout = (const float*)d_in[24];
    const float* W_node = (const float*)d_in[25];
    const float* b_node = (const float*)d_in[26];
    const float* W_fc   = (const float*)d_in[27];
    const float* b_fc   = (const float*)d_in[28];

    float*          h_agg  = (float*)((char*)d_ws + OFF_HAGG);
    unsigned short* pooled = (unsigned short*)((char*)d_ws + OFF_POOL);
    unsigned short* wpack  = (unsigned short*)((char*)d_ws + OFF_WPACK);

    pack_weights<<<896, 256, 0, stream>>>(Wqkv, Wo, W1, W2, W_eout, wpack);
    hipMemsetAsync(h_agg, 0, (size_t)N_DST_N * 128 * sizeof(float), stream);

    edge_kernel<<<E_N / 2, 256, 0, stream>>>(
        edge_features, seq_times, e_len,
        W_ein, b_ein, bqkv, bo, ln1_g, ln1_b, b1, b2, ln2_g, ln2_b,
        wpack, pooled);

    edge_out_kernel<<<E_N / 16, 256, 0, stream>>>(
        node_features, src_ids, dst_ids, pooled, wpack, b_eout, h_agg);

    node_kernel<<<N_DST_N, 128, 0, stream>>>(
        node_features, layer_nid, subg_norm, h_agg,
        W_eout, b_eout, W_node, b_node, W_fc, b_fc, (float*)d_out);
}

// Round 4
// 827.698 us; speedup vs baseline: 4.6937x; 1.0735x over previous
//
#include <hip/hip_runtime.h>

typedef __attribute__((ext_vector_type(8))) short bf16x8;
typedef __attribute__((ext_vector_type(4))) short s16x4;
typedef __attribute__((ext_vector_type(4))) float f32x4;

#define E_N      32768
#define N_DST_N  5000
#define NCLS     10

// ---- workspace layout (bytes) ----
#define OFF_HAGG   0            // f32 [5000][128]
#define OFF_POOL   2560000      // bf16 [32768][128]
#define OFF_WPACK  10948608     // bf16 packed fragments, 233472 elems

// packed-weight offsets in bf16x8 (8-elem) units
#define PK_QKV(l)  ((l) * 6144)
#define PK_WO(l)   (12288 + (l) * 2048)
#define PK_W1(l)   (16384 + (l) * 2048)
#define PK_W2(l)   (20480 + (l) * 2048)
#define PK_WEOUT   24576
#define PK_WEIN    28672

__device__ __forceinline__ unsigned short f2bf(float f) {
    unsigned int u = __float_as_uint(f);
    u += 0x7fffu + ((u >> 16) & 1u);         // RNE
    return (unsigned short)(u >> 16);
}

// ---------------------------------------------------------------------------
// Pack weights into bf16 B-fragment order:
// dst[((t*(K/32)+kk)*64 + lane)*8 + j] = W[k][n],
//   n = t*16 + (lane&15), k = kk*32 + (lane>>4)*8 + j.
// W_ein packed in a K=32 frame with zeros for k>=16.
// ---------------------------------------------------------------------------
__global__ void pack_weights(const float* __restrict__ Wqkv,
                             const float* __restrict__ Wo,
                             const float* __restrict__ W1,
                             const float* __restrict__ W2,
                             const float* __restrict__ W_eout,
                             const float* __restrict__ W_ein,
                             unsigned short* __restrict__ wpack) {
    int gid = blockIdx.x * 256 + threadIdx.x;
    if (gid >= 233472) return;
    if (gid >= 229376) {                     // W_ein section (K=16 padded to 32)
        int li = gid - 229376;
        int j = li & 7, lane = (li >> 3) & 63, t = li >> 9;
        int k = ((lane >> 4) << 3) + j;
        int n = t * 16 + (lane & 15);
        wpack[gid] = (k < 16) ? f2bf(W_ein[k * 128 + n]) : (unsigned short)0;
        return;
    }
    int id = gid;
    const float* src; int K, N, li;
    if (id < 98304)       { src = Wqkv + (id / 49152) * 49152; li = id % 49152; K = 128; N = 384; }
    else if (id < 131072) { id -= 98304;  src = Wo + (id / 16384) * 16384; li = id % 16384; K = 128; N = 128; }
    else if (id < 163840) { id -= 131072; src = W1 + (id / 16384) * 16384; li = id % 16384; K = 128; N = 128; }
    else if (id < 196608) { id -= 163840; src = W2 + (id / 16384) * 16384; li = id % 16384; K = 128; N = 128; }
    else                  { li = id - 196608; src = W_eout; K = 256; N = 128; }
    int j = li & 7, lane = (li >> 3) & 63, rest = li >> 9;
    int ks = K >> 5;
    int kk = rest % ks, t = rest / ks;
    int k = kk * 32 + ((lane >> 4) << 3) + j;
    int n = t * 16 + (lane & 15);
    wpack[gid] = f2bf(src[k * N + n]);
}

// ---------------------------------------------------------------------------
// LayerNorm over register residual (C-layout). Thread owns cols
// cA=w*32+c16, cB=cA+16, rows {rt*16 + row4 + r}. In-wave shfl reduce over
// c16, cross-wave via psum/psq partial tables. Writes bf16 a_bf mirror.
// Contains one internal __syncthreads (all threads must call).
// ---------------------------------------------------------------------------
__device__ __forceinline__ void layer_norm_reg(
    float res[2][2][4],
    const float gcol[2], const float bcol[2],
    unsigned short (*a_bf)[136],
    float (*psum)[4], float (*psq)[4],
    int w, int c16, int row4)
{
    float sv[2][4], qv[2][4];
#pragma unroll
    for (int rt = 0; rt < 2; ++rt)
#pragma unroll
        for (int r = 0; r < 4; ++r) {
            float x0 = res[rt][0][r], x1 = res[rt][1][r];
            float s = x0 + x1;
            float q = x0 * x0 + x1 * x1;
#pragma unroll
            for (int d = 1; d < 16; d <<= 1) {
                s += __shfl_xor(s, d);
                q += __shfl_xor(q, d);
            }
            sv[rt][r] = s; qv[rt][r] = q;
        }
    if (c16 == 0) {
#pragma unroll
        for (int rt = 0; rt < 2; ++rt)
#pragma unroll
            for (int r = 0; r < 4; ++r) {
                int row = rt * 16 + row4 + r;
                psum[row][w] = sv[rt][r];
                psq[row][w]  = qv[rt][r];
            }
    }
    __syncthreads();
#pragma unroll
    for (int rt = 0; rt < 2; ++rt)
#pragma unroll
        for (int r = 0; r < 4; ++r) {
            int row = rt * 16 + row4 + r;
            float4 S = *(const float4*)&psum[row][0];
            float4 Q = *(const float4*)&psq[row][0];
            float sum = (S.x + S.y) + (S.z + S.w);
            float sq  = (Q.x + Q.y) + (Q.z + Q.w);
            float mu  = sum * (1.f / 128.f);
            float var = sq * (1.f / 128.f) - mu * mu;
            float inv = rsqrtf(var + 1e-5f);
#pragma unroll
            for (int ti = 0; ti < 2; ++ti) {
                float y = (res[rt][ti][r] - mu) * inv * gcol[ti] + bcol[ti];
                res[rt][ti][r] = y;
                a_bf[row][w * 32 + ti * 16 + c16] = f2bf(y);
            }
        }
}

// ---------------------------------------------------------------------------
// Edge mega-kernel: one block (4 waves) per TWO edges. All matmuls AND
// attention on MFMA; residual stream in registers; LN via shfl+partials.
// ---------------------------------------------------------------------------
__global__ __launch_bounds__(256, 3) void edge_kernel(
    const float* __restrict__ edge_features,   // [E,16,15]
    const float* __restrict__ seq_times,       // [E,16]
    const int*   __restrict__ e_len,
    const float* __restrict__ b_ein,
    const float* __restrict__ bqkv,  const float* __restrict__ bo,
    const float* __restrict__ ln1_g, const float* __restrict__ ln1_b,
    const float* __restrict__ b1,    const float* __restrict__ b2,
    const float* __restrict__ ln2_g, const float* __restrict__ ln2_b,
    const unsigned short* __restrict__ wpack,
    unsigned short* __restrict__ pooled)       // [E,128] bf16
{
    __shared__ __align__(16) unsigned short a_bf[32][136];  // LN-out / Q / ctx
    __shared__ __align__(16) unsigned short k_bf[32][136];  // K
    __shared__ __align__(16) unsigned short vT[2][128][24]; // V transposed [d][s]
    __shared__ __align__(16) unsigned short x_bf[32][40];   // input, cols16..31 = 0
    __shared__ __align__(16) float psum[32][4];
    __shared__ __align__(16) float psq[32][4];

    const int tid  = threadIdx.x;
    const int e0   = blockIdx.x * 2;
    const int lane = tid & 63;
    const int w    = tid >> 6;
    const int c16  = lane & 15;
    const int g    = lane >> 4;
    const int row4 = g << 2;
    const int kblk = g << 3;
    const int len0 = e_len[e0];
    const int len1 = e_len[e0 + 1];
    const f32x4 z4 = {0.f, 0.f, 0.f, 0.f};

    float res[2][2][4];          // [edge rt][col ti][row r]

    // LN params for this thread's two columns
    float lnG[2][2][2], lnB[2][2][2];    // [layer][ln#][ti]
#pragma unroll
    for (int l = 0; l < 2; ++l)
#pragma unroll
        for (int ti = 0; ti < 2; ++ti) {
            int col = w * 32 + ti * 16 + c16;
            lnG[l][0][ti] = ln1_g[l * 128 + col];
            lnB[l][0][ti] = ln1_b[l * 128 + col];
            lnG[l][1][ti] = ln2_g[l * 128 + col];
            lnB[l][1][ti] = ln2_b[l * 128 + col];
        }

    // ---- stage input (cols 16..31 zeroed for K=32 padding) ----
    for (int idx = tid; idx < 1024; idx += 256) {
        int r = idx >> 5, cc = idx & 31;
        int e = r >> 4, s = r & 15;
        float v = 0.f;
        if (cc < 15)       v = edge_features[(e0 + e) * 240 + s * 15 + cc];
        else if (cc == 15) v = seq_times[(e0 + e) * 16 + s];
        x_bf[r][cc] = f2bf(v);
    }
    __syncthreads();

    const bf16x8* WP = (const bf16x8*)wpack;

    // ---- embed: relu(x @ W_ein + b) via MFMA (K=16 padded to 32) ----
    {
        bf16x8 axf[2];
#pragma unroll
        for (int rt = 0; rt < 2; ++rt)
            axf[rt] = *(const bf16x8*)&x_bf[rt * 16 + c16][kblk];
#pragma unroll
        for (int ti = 0; ti < 2; ++ti) {
            bf16x8 bw = WP[PK_WEIN + (2 * w + ti) * 64 + lane];
            int col = (2 * w + ti) * 16 + c16;
            float bias = b_ein[col];
#pragma unroll
            for (int rt = 0; rt < 2; ++rt) {
                f32x4 acc = __builtin_amdgcn_mfma_f32_16x16x32_bf16(axf[rt], bw, z4, 0, 0, 0);
#pragma unroll
                for (int r = 0; r < 4; ++r) {
                    float v = fmaxf(acc[r] + bias, 0.f);
                    res[rt][ti][r] = v;
                    a_bf[rt * 16 + row4 + r][col] = f2bf(v);
                }
            }
        }
    }
    __syncthreads();

    for (int l = 0; l < 2; ++l) {
        // ---- QKV: Q -> a_bf (reuse), K -> k_bf, V -> vT (transposed) ----
        {
            bf16x8 af[2][4];
#pragma unroll
            for (int rt = 0; rt < 2; ++rt)
#pragma unroll
                for (int kk = 0; kk < 4; ++kk)
                    af[rt][kk] = *(const bf16x8*)&a_bf[rt * 16 + c16][kk * 32 + kblk];
            __syncthreads();   // all af reads done before Q overwrites a_bf
            const bf16x8* B = WP + PK_QKV(l);
#pragma unroll
            for (int seg = 0; seg < 3; ++seg) {
                bf16x8 bq[2][4];
#pragma unroll
                for (int ti = 0; ti < 2; ++ti)
#pragma unroll
                    for (int kk = 0; kk < 4; ++kk)
                        bq[ti][kk] = B[((seg * 8 + 2 * w + ti) * 4 + kk) * 64 + lane];
#pragma unroll
                for (int ti = 0; ti < 2; ++ti) {
                    int col = (2 * w + ti) * 16 + c16;
                    float bias = bqkv[l * 384 + seg * 128 + col];
#pragma unroll
                    for (int rt = 0; rt < 2; ++rt) {
                        f32x4 acc = z4;
#pragma unroll
                        for (int kk = 0; kk < 4; ++kk)
                            acc = __builtin_amdgcn_mfma_f32_16x16x32_bf16(
                                af[rt][kk], bq[ti][kk], acc, 0, 0, 0);
                        if (seg == 0) {
#pragma unroll
                            for (int r = 0; r < 4; ++r)
                                a_bf[rt * 16 + row4 + r][col] = f2bf(acc[r] + bias);
                        } else if (seg == 1) {
#pragma unroll
                            for (int r = 0; r < 4; ++r)
                                k_bf[rt * 16 + row4 + r][col] = f2bf(acc[r] + bias);
                        } else {
                            s16x4 pk;
#pragma unroll
                            for (int r = 0; r < 4; ++r)
                                pk[r] = (short)f2bf(acc[r] + bias);
                            *(s16x4*)&vT[rt][col][row4] = pk;   // V^T[d][s]
                        }
                    }
                }
            }
        }
        __syncthreads();

        // ---- attention via MFMA: S^T = K@Q^T, ctx^T = V^T@P^T ----
#pragma unroll
        for (int i = 0; i < 4; ++i) {
            int pp = w * 4 + i;
            int e  = pp >> 3;
            int hb = (pp & 7) * 16;
            int er = e * 16;
            int len = e ? len1 : len0;
            bf16x8 kf = {0,0,0,0,0,0,0,0};
            bf16x8 qf = {0,0,0,0,0,0,0,0};
            bf16x8 vf = {0,0,0,0,0,0,0,0};
            if (lane < 32) {   // dh = kblk+j < 16 only
                kf = *(const bf16x8*)&k_bf[er + c16][hb + kblk];
                qf = *(const bf16x8*)&a_bf[er + c16][hb + kblk];
                vf = *(const bf16x8*)&vT[e][hb + c16][kblk];
            }
            f32x4 st = __builtin_amdgcn_mfma_f32_16x16x32_bf16(kf, qf, z4, 0, 0, 0);
            // lane holds S^T[k=4g+r][q=c16]
            float sv[4]; float mx = -1e30f;
#pragma unroll
            for (int r = 0; r < 4; ++r) {
                sv[r] = st[r] * 0.25f;
                if (4 * g + r < len) mx = fmaxf(mx, sv[r]);
            }
            mx = fmaxf(mx, __shfl_xor(mx, 16));
            mx = fmaxf(mx, __shfl_xor(mx, 32));
            float p[4]; float sum = 0.f;
#pragma unroll
            for (int r = 0; r < 4; ++r) {
                float pe = (4 * g + r < len) ? __expf(sv[r] - mx) : 0.f;
                p[r] = pe; sum += pe;
            }
            sum += __shfl_xor(sum, 16);
            sum += __shfl_xor(sum, 32);
            float inv = __fdividef(1.f, sum);
            unsigned int own0 = (unsigned int)f2bf(p[0] * inv) | ((unsigned int)f2bf(p[1] * inv) << 16);
            unsigned int own1 = (unsigned int)f2bf(p[2] * inv) | ((unsigned int)f2bf(p[3] * inv) << 16);
            // regroup P^T (C-layout, 4 k/lane) into B-frag layout (8 k/lane)
            unsigned int t0a = (unsigned int)__shfl((int)own0, (lane + 16) & 63);
            unsigned int t1a = (unsigned int)__shfl((int)own1, (lane + 16) & 63);
            unsigned int t0b = (unsigned int)__shfl((int)own0, (lane + 32) & 63);
            unsigned int t1b = (unsigned int)__shfl((int)own1, (lane + 32) & 63);
            union { unsigned int u[4]; bf16x8 v; } pb;
            if (g == 0)      { pb.u[0] = own0; pb.u[1] = own1; pb.u[2] = t0a; pb.u[3] = t1a; }
            else if (g == 1) { pb.u[0] = t0a;  pb.u[1] = t1a;  pb.u[2] = t0b; pb.u[3] = t1b; }
            else             { pb.u[0] = 0; pb.u[1] = 0; pb.u[2] = 0; pb.u[3] = 0; }
            f32x4 ct = __builtin_amdgcn_mfma_f32_16x16x32_bf16(vf, pb.v, z4, 0, 0, 0);
            // lane holds ctx^T[d=4g+r][q=c16] -> a_bf[er+q][hb+4g+r]
            s16x4 cpk;
#pragma unroll
            for (int r = 0; r < 4; ++r) cpk[r] = (short)f2bf(ct[r]);
            *(s16x4*)&a_bf[er + c16][hb + 4 * g] = cpk;
        }
        __syncthreads();

        // ---- proj + residual (registers) ----
        {
            bf16x8 af[2][4];
#pragma unroll
            for (int rt = 0; rt < 2; ++rt)
#pragma unroll
                for (int kk = 0; kk < 4; ++kk)
                    af[rt][kk] = *(const bf16x8*)&a_bf[rt * 16 + c16][kk * 32 + kblk];
            const bf16x8* B = WP + PK_WO(l);
            bf16x8 bw[2][4];
#pragma unroll
            for (int ti = 0; ti < 2; ++ti)
#pragma unroll
                for (int kk = 0; kk < 4; ++kk)
                    bw[ti][kk] = B[((2 * w + ti) * 4 + kk) * 64 + lane];
#pragma unroll
            for (int ti = 0; ti < 2; ++ti) {
                int col = (2 * w + ti) * 16 + c16;
                float bias = bo[l * 128 + col];
#pragma unroll
                for (int rt = 0; rt < 2; ++rt) {
                    f32x4 acc = z4;
#pragma unroll
                    for (int kk = 0; kk < 4; ++kk)
                        acc = __builtin_amdgcn_mfma_f32_16x16x32_bf16(
                            af[rt][kk], bw[ti][kk], acc, 0, 0, 0);
#pragma unroll
                    for (int r = 0; r < 4; ++r)
                        res[rt][ti][r] += acc[r] + bias;
                }
            }
        }
        layer_norm_reg(res, lnG[l][0], lnB[l][0], a_bf, psum, psq, w, c16, row4);
        __syncthreads();

        // ---- FF1: relu(e @ W1 + b1) -> a_bf ----
        {
            bf16x8 af[2][4];
#pragma unroll
            for (int rt = 0; rt < 2; ++rt)
#pragma unroll
                for (int kk = 0; kk < 4; ++kk)
                    af[rt][kk] = *(const bf16x8*)&a_bf[rt * 16 + c16][kk * 32 + kblk];
            const bf16x8* B = WP + PK_W1(l);
            bf16x8 bw[2][4];
#pragma unroll
            for (int ti = 0; ti < 2; ++ti)
#pragma unroll
                for (int kk = 0; kk < 4; ++kk)
                    bw[ti][kk] = B[((2 * w + ti) * 4 + kk) * 64 + lane];
            f32x4 acc2[2][2];
#pragma unroll
            for (int ti = 0; ti < 2; ++ti)
#pragma unroll
                for (int rt = 0; rt < 2; ++rt) {
                    f32x4 acc = z4;
#pragma unroll
                    for (int kk = 0; kk < 4; ++kk)
                        acc = __builtin_amdgcn_mfma_f32_16x16x32_bf16(
                            af[rt][kk], bw[ti][kk], acc, 0, 0, 0);
                    acc2[ti][rt] = acc;
                }
            __syncthreads();   // all af reads done before overwrite
#pragma unroll
            for (int ti = 0; ti < 2; ++ti) {
                int col = (2 * w + ti) * 16 + c16;
                float bias = b1[l * 128 + col];
#pragma unroll
                for (int rt = 0; rt < 2; ++rt)
#pragma unroll
                    for (int r = 0; r < 4; ++r)
                        a_bf[rt * 16 + row4 + r][col] =
                            f2bf(fmaxf(acc2[ti][rt][r] + bias, 0.f));
            }
        }
        __syncthreads();

        // ---- FF2 + residual (registers) ----
        {
            bf16x8 af[2][4];
#pragma unroll
            for (int rt = 0; rt < 2; ++rt)
#pragma unroll
                for (int kk = 0; kk < 4; ++kk)
                    af[rt][kk] = *(const bf16x8*)&a_bf[rt * 16 + c16][kk * 32 + kblk];
            const bf16x8* B = WP + PK_W2(l);
            bf16x8 bw[2][4];
#pragma unroll
            for (int ti = 0; ti < 2; ++ti)
#pragma unroll
                for (int kk = 0; kk < 4; ++kk)
                    bw[ti][kk] = B[((2 * w + ti) * 4 + kk) * 64 + lane];
#pragma unroll
            for (int ti = 0; ti < 2; ++ti) {
                int col = (2 * w + ti) * 16 + c16;
                float bias = b2[l * 128 + col];
#pragma unroll
                for (int rt = 0; rt < 2; ++rt) {
                    f32x4 acc = z4;
#pragma unroll
                    for (int kk = 0; kk < 4; ++kk)
                        acc = __builtin_amdgcn_mfma_f32_16x16x32_bf16(
                            af[rt][kk], bw[ti][kk], acc, 0, 0, 0);
#pragma unroll
                    for (int r = 0; r < 4; ++r)
                        res[rt][ti][r] += acc[r] + bias;
                }
            }
        }
        layer_norm_reg(res, lnG[l][1], lnB[l][1], a_bf, psum, psq, w, c16, row4);
        __syncthreads();
    }

    // ---- masked mean pool (from registers) -> pooled bf16 ----
#pragma unroll
    for (int rt = 0; rt < 2; ++rt) {
        int len = rt ? len1 : len0;
        float fln = (float)len;
#pragma unroll
        for (int ti = 0; ti < 2; ++ti) {
            float s = 0.f;
#pragma unroll
            for (int r = 0; r < 4; ++r)
                if (row4 + r < len) s += res[rt][ti][r];
            s += __shfl_xor(s, 16);
            s += __shfl_xor(s, 32);
            if (lane < 16)
                pooled[(e0 + rt) * 128 + w * 32 + ti * 16 + c16] = f2bf(s / fln);
        }
    }
}

// ---------------------------------------------------------------------------
// Edge-out: m = relu(concat(h[src], pooled) @ W_eout + b_eout), 16 edges/blk,
// atomic scatter into h_agg.
// ---------------------------------------------------------------------------
__global__ __launch_bounds__(256) void edge_out_kernel(
    const float* __restrict__ node_features,
    const int* __restrict__ src_ids, const int* __restrict__ dst_ids,
    const unsigned short* __restrict__ pooled,
    const unsigned short* __restrict__ wpack,
    const float* __restrict__ b_eout,
    float* __restrict__ h_agg)
{
    __shared__ __align__(16) unsigned short a2[16][264];
    __shared__ int dst_s[16];
    const int tid = threadIdx.x, lane = tid & 63, w = tid >> 6;
    const int e0 = blockIdx.x * 16;

    {
        int r = tid >> 4, cm = tid & 15;
        int e = e0 + r;
        int src = src_ids[e];
#pragma unroll
        for (int m = 0; m < 8; ++m) {
            int col = cm + 16 * m;
            a2[r][col] = f2bf(node_features[src * 128 + col]);
        }
#pragma unroll
        for (int m = 0; m < 8; ++m) {
            int col = cm + 16 * m;
            a2[r][128 + col] = pooled[e * 128 + col];
        }
        if (tid < 16) dst_s[tid] = dst_ids[e0 + tid];
    }
    __syncthreads();

    const int c16 = lane & 15, row4 = (lane >> 4) << 2, kblk = (lane >> 4) << 3;
    bf16x8 af[8];
#pragma unroll
    for (int kk = 0; kk < 8; ++kk)
        af[kk] = *(const bf16x8*)&a2[c16][kk * 32 + kblk];
    const bf16x8* B = (const bf16x8*)wpack + PK_WEOUT;
#pragma unroll
    for (int ti = 0; ti < 2; ++ti) {
        int t = w * 2 + ti;
        f32x4 acc = {0.f, 0.f, 0.f, 0.f};
#pragma unroll
        for (int kk = 0; kk < 8; ++kk)
            acc = __builtin_amdgcn_mfma_f32_16x16x32_bf16(
                af[kk], B[(t * 8 + kk) * 64 + lane], acc, 0, 0, 0);
        int col = t * 16 + c16;
        float bias = b_eout[col];
#pragma unroll
        for (int r = 0; r < 4; ++r) {
            int row = row4 + r;
            float v = fmaxf(acc[r] + bias, 0.f);
            atomicAdd(&h_agg[dst_s[row] * 128 + col], v);
        }
    }
}

// ---------------------------------------------------------------------------
// Node update: one block (128 threads) per destination node.
// ---------------------------------------------------------------------------
__global__ __launch_bounds__(128) void node_kernel(
    const float* __restrict__ node_features,
    const int*   __restrict__ layer_nid,
    const float* __restrict__ subg_norm,
    const float* __restrict__ h_agg,
    const float* __restrict__ W_eout, const float* __restrict__ b_eout,
    const float* __restrict__ W_node, const float* __restrict__ b_node,
    const float* __restrict__ W_fc,   const float* __restrict__ b_fc,
    float* __restrict__ out)
{
    __shared__ float sh[128];
    __shared__ float hh[128];
    __shared__ float z[128];

    const int n   = blockIdx.x;
    const int tid = threadIdx.x;
    const int nid = layer_nid[n];
    const float norm = subg_norm[n];

    sh[tid] = node_features[nid * 128 + tid];
    __syncthreads();

    float acc = 0.f;
#pragma unroll 4
    for (int k = 0; k < 128; ++k)
        acc = fmaf(sh[k], W_eout[k * 128 + tid], acc);
    acc += b_eout[tid];
    hh[tid] = (h_agg[n * 128 + tid] - acc) * norm;
    __syncthreads();

    float za = 0.f;
#pragma unroll 4
    for (int k = 0; k < 128; ++k)
        za = fmaf(sh[k], W_node[k * 128 + tid], za);
#pragma unroll 4
    for (int k = 0; k < 128; ++k)
        za = fmaf(hh[k], W_node[(128 + k) * 128 + tid], za);
    za += b_node[tid];
    z[tid] = fmaxf(za, 0.f);
    __syncthreads();

    if (tid < NCLS) {
        float o = 0.f;
#pragma unroll 4
        for (int k = 0; k < 128; ++k)
            o = fmaf(z[k], W_fc[k * NCLS + tid], o);
        out[n * NCLS + tid] = o + b_fc[tid];
    }
}

// ---------------------------------------------------------------------------

extern "C" void kernel_launch(void* const* d_in, const int* in_sizes, int n_in,
                              void* d_out, int out_size, void* d_ws, size_t ws_size,
                              hipStream_t stream) {
    const float* node_features = (const float*)d_in[0];
    const float* edge_features = (const float*)d_in[1];
    const float* seq_times     = (const float*)d_in[2];
    const int*   e_len         = (const int*)d_in[3];
    // d_in[4] = e_mask (recomputed from e_len)
    const int*   src_ids       = (const int*)d_in[5];
    const int*   dst_ids       = (const int*)d_in[6];
    const int*   layer_nid     = (const int*)d_in[7];
    const float* subg_norm     = (const float*)d_in[8];
    const float* W_ein  = (const float*)d_in[9];
    const float* b_ein  = (const float*)d_in[10];
    const float* Wqkv   = (const float*)d_in[11];
    const float* bqkv   = (const float*)d_in[12];
    const float* Wo     = (const float*)d_in[13];
    const float* bo     = (const float*)d_in[14];
    const float* ln1_g  = (const float*)d_in[15];
    const float* ln1_b  = (const float*)d_in[16];
    const float* W1     = (const float*)d_in[17];
    const float* b1     = (const float*)d_in[18];
    const float* W2     = (const float*)d_in[19];
    const float* b2     = (const float*)d_in[20];
    const float* ln2_g  = (const float*)d_in[21];
    const float* ln2_b  = (const float*)d_in[22];
    const float* W_eout = (const float*)d_in[23];
    const float* b_eout = (const float*)d_in[24];
    const float* W_node = (const float*)d_in[25];
    const float* b_node = (const float*)d_in[26];
    const float* W_fc   = (const float*)d_in[27];
    const float* b_fc   = (const float*)d_in[28];

    float*          h_agg  = (float*)((char*)d_ws + OFF_HAGG);
    unsigned short* pooled = (unsigned short*)((char*)d_ws + OFF_POOL);
    unsigned short* wpack  = (unsigned short*)((char*)d_ws + OFF_WPACK);

    pack_weights<<<912, 256, 0, stream>>>(Wqkv, Wo, W1, W2, W_eout, W_ein, wpack);
    hipMemsetAsync(h_agg, 0, (size_t)N_DST_N * 128 * sizeof(float), stream);

    edge_kernel<<<E_N / 2, 256, 0, stream>>>(
        edge_features, seq_times, e_len,
        b_ein, bqkv, bo, ln1_g, ln1_b, b1, b2, ln2_g, ln2_b,
        wpack, pooled);

    edge_out_kernel<<<E_N / 16, 256, 0, stream>>>(
        node_features, src_ids, dst_ids, pooled, wpack, b_eout, h_agg);

    node_kernel<<<N_DST_N, 128, 0, stream>>>(
        node_features, layer_nid, subg_norm, h_agg,
        W_eout, b_eout, W_node, b_node, W_fc, b_fc, (float*)d_out);
}